// Round 11
// baseline (4907.435 us; speedup 1.0000x reference)
//
#include <hip/hip_runtime.h>

#define Nb   256
#define Tt   2048
#define INs  6
#define HID  128
#define STs  64
#define LAY  134
#define OUTs 6
#define NDW  68      // activation dwords: 134 f16 slots + 2 pad
#define HPAD 132     // Hhist/WolT row stride in floats (bank-spread)

typedef __fp16 f16x2 __attribute__((ext_vector_type(2)));
typedef __fp16 f16x8 __attribute__((ext_vector_type(8)));

__device__ __forceinline__ float exp2_fast(float x) {
#if __has_builtin(__builtin_amdgcn_exp2f)
    return __builtin_amdgcn_exp2f(x);
#else
    return exp2f(x);
#endif
}
__device__ __forceinline__ float rcp_fast(float x) {
#if __has_builtin(__builtin_amdgcn_rcpf)
    return __builtin_amdgcn_rcpf(x);
#else
    return 1.0f / x;
#endif
}
__device__ __forceinline__ float tanh_fast(float x) {
    float e = exp2_fast(x * 2.8853900817779268f);
    return 1.0f - 2.0f * rcp_fast(e + 1.0f);
}
__device__ __forceinline__ unsigned pack2(float a, float b) {
#if __has_builtin(__builtin_amdgcn_cvt_pkrtz)
    union { f16x2 h; unsigned u; } u;
    u.h = __builtin_amdgcn_cvt_pkrtz(a, b);
    return u.u;
#else
    union { f16x2 h; unsigned u; } u;
    u.h[0] = (__fp16)a; u.h[1] = (__fp16)b;
    return u.u;
#endif
}
__device__ __forceinline__ unsigned pack2w(float a, float b) {   // RNE (weights)
    union { f16x2 h; unsigned u; } u;
    u.h[0] = (__fp16)a; u.h[1] = (__fp16)b;
    return u.u;
}
__device__ __forceinline__ float dot2p(unsigned av, f16x2 wv, float c) {
    union { unsigned u; f16x2 f; } ua; ua.u = av;
#if __has_builtin(__builtin_amdgcn_fdot2)
    return __builtin_amdgcn_fdot2(ua.f, wv, c, false);
#else
    return c + (float)ua.f[0] * (float)wv[0] + (float)ua.f[1] * (float)wv[1];
#endif
}
__device__ __forceinline__ float dotdw(unsigned av, unsigned wv, float c) {
    union { unsigned u; f16x2 f; } uw; uw.u = wv;
    return dot2p(av, uw.f, c);
}

#define WR17(M) M(0) M(1) M(2) M(3) M(4) M(5) M(6) M(7) M(8) M(9) M(10) M(11) M(12) M(13) M(14) M(15) M(16)

#define DECLW(k) f16x8 w##k = {};
// rows 8k..8k+7 of column `col`, stride od; rows >= LAY zero
#define LOADW(k) { f16x8 tmp; \
    _Pragma("unroll") for (int q = 0; q < 8; ++q) { int r = 8*(k)+q; \
        float f = (r < LAY) ? Wsrc[r * od + col] : 0.f; tmp[q] = (__fp16)f; } \
    w##k = tmp; }

#define LOADX17(buf) const uint4* a4_ = (const uint4*)(buf); \
    uint4 x0=a4_[0],x1=a4_[1],x2=a4_[2],x3=a4_[3],x4=a4_[4],x5=a4_[5],x6=a4_[6],x7=a4_[7], \
          x8=a4_[8],x9=a4_[9],x10=a4_[10],x11=a4_[11],x12=a4_[12],x13=a4_[13],x14=a4_[14], \
          x15=a4_[15],x16=a4_[16]

#define DOTK(k) { \
    a0 = dot2p(x##k.x, __builtin_shufflevector(w##k, w##k, 0, 1), a0); \
    a1 = dot2p(x##k.y, __builtin_shufflevector(w##k, w##k, 2, 3), a1); \
    a2 = dot2p(x##k.z, __builtin_shufflevector(w##k, w##k, 4, 5), a2); \
    a3 = dot2p(x##k.w, __builtin_shufflevector(w##k, w##k, 6, 7), a3); }
#define DOTSET WR17(DOTK)

#define OVK(k) { uint4 wv = w4_[k]; o0=dotdw(x##k.x,wv.x,o0); o1=dotdw(x##k.y,wv.y,o1); \
                 o2=dotdw(x##k.z,wv.z,o2); o3=dotdw(x##k.w,wv.w,o3); }
#define OVSET WR17(OVK)

// 768 threads, 12 waves, 1 block/CU (LDS ~93 KB) -> 3 waves/SIMD -> ~168 VGPR budget.
// grp = tid>>8: 0 -> gates layer 1 (P1), 1 -> gates layer 2 (P2), 2 -> alpha/beta (P3).
// Within group: col = (tid&255)>>1 (0..127), mat = tid&1 (Wg1/Wg2 or Wa/Wb).
// Each thread: ONE 17xf16x8 weight-column set (68 VGPRs) -> activation stream fits too.
// Gate cols 128..133 (x2 mats): LDS-streamed by 12 idle-group threads per phase.
// beta crosses mat via shfl_xor(1) in-wave -> 3 barriers/step. H -> 64-step LDS ring,
// flushed as 384 coalesced stores every 64 steps (no per-step store drain).
__global__ __launch_bounds__(768, 1) __attribute__((amdgpu_waves_per_eu(3, 3)))
void lmsc_kernel(const float* __restrict__ X,  const float* __restrict__ H0,
                 const float* __restrict__ Wg1, const float* __restrict__ bg1,
                 const float* __restrict__ Wg2, const float* __restrict__ bg2,
                 const float* __restrict__ Wa,  const float* __restrict__ ba,
                 const float* __restrict__ Wb,  const float* __restrict__ bb,
                 const float* __restrict__ Wh,  const float* __restrict__ bh,
                 const float* __restrict__ Wo,  const float* __restrict__ bo,
                 float* __restrict__ out)
{
    __shared__ float Xls[Tt * INs];                   // 48 KB
    __shared__ alignas(16) float Hhist[64][HPAD];     // 33.8 KB H ring
    __shared__ alignas(16) float WolT[OUTs][HPAD];    // 3.2 KB transposed Wo
    __shared__ alignas(16) unsigned OvW[2][12][NDW];  // 6.5 KB overhang gate cols
    __shared__ alignas(16) unsigned LvX[NDW];
    __shared__ alignas(16) unsigned LvB[NDW];
    __shared__ alignas(16) unsigned LvC[NDW];
    __shared__ float H0l[STs];
    __shared__ float bol[OUTs];
    __shared__ float nrm[2];

    const int tid = threadIdx.x;
    const int n   = blockIdx.x;
    const int grp = tid >> 8;
    const int loc = tid & 255;
    const int col = loc >> 1;
    const int mat = tid & 1;
    __fp16* LvX16 = (__fp16*)LvX;
    __fp16* LvB16 = (__fp16*)LvB;
    __fp16* LvC16 = (__fp16*)LvC;

    // ---------------- staging ----------------
    {
        const float4* Xg  = (const float4*)(X + (size_t)n * (Tt * INs));
        float4*       Xl4 = (float4*)Xls;
        for (int i = tid; i < (Tt * INs) / 4; i += 768) Xl4[i] = Xg[i];
    }
    if (tid < STs) H0l[tid] = H0[n * STs + tid];
    if (tid < OUTs * HID) { int o = tid >> 7, l2 = tid & 127; WolT[o][l2] = Wo[l2 * OUTs + o]; }
    if (tid >= 770 - OUTs) {}
    if (tid < OUTs + 768 && tid >= 768 - OUTs) {}   // (no-op; keep simple below)
    if (tid < OUTs) bol[tid] = bo[tid];             // overlaps WolT cond; both cheap
    if (tid == 700) { LvX[NDW-1] = 0u; LvB[NDW-1] = 0u; LvC[NDW-1] = 0u; }
    if (tid >= 32 && tid < 56) {                    // overhang cols -> LDS
        int i = tid - 32, L = i / 12, d = i % 12;
        int c = 128 + (d >> 1), m = d & 1;
        const float* src = (m ? Wg2 : Wg1) + L * LAY * LAY;
        unsigned* dst = OvW[L][d];
        for (int q = 0; q < NDW; ++q) {
            int r0 = 2*q, r1 = 2*q + 1;
            float f0 = (r0 < LAY) ? src[r0 * LAY + c] : 0.f;
            float f1 = (r1 < LAY) ? src[r1 * LAY + c] : 0.f;
            dst[q] = pack2w(f0, f1);
        }
    }

    // ------- ONE weight-column set per thread -> 17 named f16x8 -------
    WR17(DECLW)
    float bias;
    {
        const float* Wsrc; int od;
        if (grp == 0)      { Wsrc = mat ? Wg2 : Wg1;             od = LAY; bias = (mat ? bg2 : bg1)[col]; }
        else if (grp == 1) { Wsrc = (mat ? Wg2 : Wg1) + LAY*LAY; od = LAY; bias = (mat ? bg2 : bg1)[LAY + col]; }
        else               { Wsrc = mat ? Wb : Wa;               od = HID; bias = (mat ? bb : ba)[col]; }
        WR17(LOADW)
    }
    float ovb = 0.f;
    if (tid >= 512 && tid < 524) { int s = tid - 512; ovb = ((s & 1) ? bg2 : bg1)[128 + (s >> 1)]; }
    else if (tid < 12)           { ovb = ((tid & 1) ? bg2 : bg1)[LAY + 128 + (tid >> 1)]; }
    __syncthreads();

    // ---------------- init: S0 ; norm_0 ; x-part ----------------
    float h = 0.f;
    if (grp == 2 && !mat) {
        float s = bh[col];
        for (int k = 0; k < STs; ++k) s += H0l[k] * Wh[k * HID + col];
        h = s;
        LvX16[6 + col] = (__fp16)s;
    }
    if (tid == 760) {
        float s = 0.f;
#pragma unroll
        for (int i = 0; i < 6; ++i) s += Xls[i] * Xls[i];
        float nv = sqrtf(s), rn = rcp_fast(nv);
        nrm[0] = nv;
        LvX[0] = pack2(Xls[0]*rn, Xls[1]*rn);
        LvX[1] = pack2(Xls[2]*rn, Xls[3]*rn);
        LvX[2] = pack2(Xls[4]*rn, Xls[5]*rn);
    }
    __syncthreads();

    const float LOG2E = 1.4426950408889634f;

#pragma unroll 1
    for (int t = 0; t < Tt; ++t) {
        unsigned nx0 = 0, nx1 = 0, nx2 = 0;              // thread 760 only
        // ---- P1: gates layer 1 (G1) ; overhang by G3[0..11] ; next norm ----
        if (grp == 0) {
            LOADX17(LvX);
            float a0 = 0.f, a1 = 0.f, a2 = 0.f, a3 = 0.f;
            DOTSET
            float s  = ((a0 + a1) + (a2 + a3)) + bias;
            float tn = tanh_fast(s);
            float to = __shfl_xor(tn, 1, 64);
            if (!mat) LvB16[col] = (__fp16)(tn * to);
        } else if (tid >= 512 && tid < 524) {
            int s9 = tid - 512;
            LOADX17(LvX);
            const uint4* w4_ = (const uint4*)OvW[0][s9];
            float o0 = 0.f, o1 = 0.f, o2 = 0.f, o3 = 0.f;
            OVSET
            float so = ((o0 + o1) + (o2 + o3)) + ovb;
            float tn = tanh_fast(so);
            float to = __shfl_xor(tn, 1, 64);
            if (!(s9 & 1)) LvB16[128 + (s9 >> 1)] = (__fp16)(tn * to);
        } else if (tid == 760 && (t + 1) < Tt) {
            const float* xp = &Xls[(t + 1) * INs];
            float s = 0.f;
#pragma unroll
            for (int i = 0; i < 6; ++i) s += xp[i] * xp[i];
            float nv = sqrtf(s), rn = rcp_fast(nv);
            nrm[(t + 1) & 1] = nv;
            nx0 = pack2(xp[0]*rn, xp[1]*rn);
            nx1 = pack2(xp[2]*rn, xp[3]*rn);
            nx2 = pack2(xp[4]*rn, xp[5]*rn);
        }
        __syncthreads();
        // ---- P2: gates layer 2 (G2) ; overhang by G1[0..11] ; x-part write ----
        if (grp == 1) {
            LOADX17(LvB);
            float a0 = 0.f, a1 = 0.f, a2 = 0.f, a3 = 0.f;
            DOTSET
            float s  = ((a0 + a1) + (a2 + a3)) + bias;
            float tn = tanh_fast(s);
            float to = __shfl_xor(tn, 1, 64);
            if (!mat) LvC16[col] = (__fp16)(tn * to);
        } else if (tid < 12) {
            LOADX17(LvB);
            const uint4* w4_ = (const uint4*)OvW[1][tid];
            float o0 = 0.f, o1 = 0.f, o2 = 0.f, o3 = 0.f;
            OVSET
            float so = ((o0 + o1) + (o2 + o3)) + ovb;
            float tn = tanh_fast(so);
            float to = __shfl_xor(tn, 1, 64);
            if (!(tid & 1)) LvC16[128 + (tid >> 1)] = (__fp16)(tn * to);
        } else if (tid == 760 && (t + 1) < Tt) {
            LvX[0] = nx0; LvX[1] = nx1; LvX[2] = nx2;
        }
        __syncthreads();
        // ---- P3: alpha/beta (G3) + H update; beta via in-wave shfl ----
        if (grp == 2) {
            LOADX17(LvC);
            float a0 = 0.f, a1 = 0.f, a2 = 0.f, a3 = 0.f;
            DOTSET
            float s  = ((a0 + a1) + (a2 + a3)) + bias;
            float tn   = tanh_fast(s);                   // on mat=1: beta
            float beta = __shfl_xor(tn, 1, 64);
            if (!mat) {
                float alpha = exp2_fast(s * LOG2E);
                float e2 = exp2_fast(-alpha * nrm[t & 1] * LOG2E);
                h = e2 * (h - beta) + beta;
                Hhist[t & 63][col] = h;
                LvX16[6 + col] = (__fp16)h;
            }
        }
        __syncthreads();
        // ---- flush: 64 H rows -> Y, coalesced, every 64 steps ----
        if ((t & 63) == 63) {
            if (tid < 384) {
                int fs = tid / 6, fo = tid - fs * 6;
                float acc = bol[fo];
                const float4* hr = (const float4*)(&Hhist[fs][0]);
                const float4* wr = (const float4*)(&WolT[fo][0]);
#pragma unroll 4
                for (int k2 = 0; k2 < HID / 4; ++k2) {
                    float4 hv = hr[k2], wv = wr[k2];
                    acc += hv.x*wv.x + hv.y*wv.y + hv.z*wv.z + hv.w*wv.w;
                }
                out[((size_t)n * Tt + (t - 63)) * OUTs + tid] = acc;
            }
            __syncthreads();
        }
    }
}

extern "C" void kernel_launch(void* const* d_in, const int* in_sizes, int n_in,
                              void* d_out, int out_size, void* d_ws, size_t ws_size,
                              hipStream_t stream) {
    const float* X   = (const float*)d_in[0];
    const float* H0  = (const float*)d_in[1];
    const float* Wg1 = (const float*)d_in[2];
    const float* bg1 = (const float*)d_in[3];
    const float* Wg2 = (const float*)d_in[4];
    const float* bg2 = (const float*)d_in[5];
    const float* Wa  = (const float*)d_in[6];
    const float* ba  = (const float*)d_in[7];
    const float* Wb  = (const float*)d_in[8];
    const float* bb  = (const float*)d_in[9];
    const float* Wh  = (const float*)d_in[10];
    const float* bh  = (const float*)d_in[11];
    const float* Wo  = (const float*)d_in[12];
    const float* bo  = (const float*)d_in[13];
    float* out = (float*)d_out;

    hipLaunchKernelGGL(lmsc_kernel, dim3(Nb), dim3(768), 0, stream,
                       X, H0, Wg1, bg1, Wg2, bg2, Wa, ba, Wb, bb, Wh, bh, Wo, bo, out);
}